// Round 20
// baseline (74.284 us; speedup 1.0000x reference)
//
#include <hip/hip_runtime.h>

namespace {

constexpr int kB  = 16;    // batches
constexpr int kP  = 8;     // pieces
constexpr int kNT = 512;   // time steps (incl. t=0)
constexpr int kNX = 2048;  // cells
constexpr int kW  = 32;    // steps per super-step
constexpr int kChunk = 64;                // cells owned per wave
constexpr int kNS = 16;                   // super-steps: 15*32 + 31 = 511 rows
constexpr int kSolver = 512;              // 16 batches x 32 chunks
// region per wave = kChunk + 2*kW = 128 cells = 64 lanes x 2 cells

// d_ws layout
constexpr size_t kFlagsBytes = (size_t)kSolver * kNS * 4;   // 32 KB
constexpr size_t kHaloOff    = 65536;  // int halo[512][kNS][kChunk]; slot s=0 of
                                       // each block is never read -> per-block
                                       // dump target for non-writer lanes.

// Cross-lane shift by one lane via DPP (VALU; no LDS round-trip).
__device__ __forceinline__ float dpp_shr1(float x) {
    return __builtin_bit_cast(float,
        __builtin_amdgcn_update_dpp(0, __builtin_bit_cast(int, x), 0x138, 0xF, 0xF, true));
}
__device__ __forceinline__ float dpp_shl1(float x) {
    return __builtin_bit_cast(float,
        __builtin_amdgcn_update_dpp(0, __builtin_bit_cast(int, x), 0x130, 0xF, 0xF, true));
}

// m = max(-xL, xR, 0) in ONE VOP3 (neg modifier free). Godunov flux for
// f(u)=u(1-u) in x=u-1/2 space: F = 1/4 - m^2; the 1/4 cancels in the flux
// difference, so the update is x += lam*(G_r - G_l), G = m^2.
__device__ __forceinline__ float max3n(float xL, float xR) {
    float m;
    asm("v_max3_f32 %0, -%1, %2, 0" : "=v"(m) : "v"(xL), "v"(xR));
    return m;
}

// Agent-scope coherence-point ops (relaxed: no cache maintenance).
__device__ __forceinline__ void mall_store(int* p, float v) {
    (void)__hip_atomic_exchange(p, __builtin_bit_cast(int, v),
                                __ATOMIC_RELAXED, __HIP_MEMORY_SCOPE_AGENT);
}
__device__ __forceinline__ float mall_loadf(const int* p) {
    return __builtin_bit_cast(float,
        __hip_atomic_load(p, __ATOMIC_RELAXED, __HIP_MEMORY_SCOPE_AGENT));
}
__device__ __forceinline__ int mall_loadi(const int* p) {
    return __hip_atomic_load(p, __ATOMIC_RELAXED, __HIP_MEMORY_SCOPE_AGENT);
}

__global__ __launch_bounds__(64)
void godunov_fused(const float* __restrict__ xs,   // (B, P+1)
                   const float* __restrict__ ks,   // (B, P)
                   const int*   __restrict__ pm,   // (B, P)
                   const float* __restrict__ dxp,  // (B,)
                   const float* __restrict__ dtp,  // (B,)
                   float* __restrict__ out,        // (B,1,NT,NX) fp32
                   int*   __restrict__ flags,      // [512][kNS], pre-zeroed
                   int*   __restrict__ halo)       // [512][kNS][kChunk] f32 bits
{
    const int p    = blockIdx.x;
    const int b    = p >> 5;         // batch
    const int k    = p & 31;         // chunk within batch
    const int lane = threadIdx.x;    // 0..63, one wave per block
    const int rs   = k * kChunk - kW;    // region start (may be <0)
    const int gi0  = rs + 2 * lane;      // this lane's first cell

    const float dxv = dxp[0];
    const float lam = dtp[0] / dxv;

    // ---- piecewise-constant IC parameters ----
    int np = 0;
    float bnds[kP];
#pragma unroll
    for (int j = 0; j < kP; ++j) {
        int m = pm[b * kP + j];
        np += m;
        bnds[j] = m ? xs[b * (kP + 1) + j + 1] : __builtin_inff();
    }
    const int cap = np - 1;

    auto icval = [&](int gi) -> float {
        float xc = ((float)gi + 0.5f) * dxv;
        int idx = 0;
#pragma unroll
        for (int j = 0; j < kP; ++j) idx += (xc >= bnds[j]) ? 1 : 0;
        idx = min(idx, cap);
        return ks[b * kP + idx];
    };

    // Constant ghost values (reference: frozen IC endpoints).
    const float gL = icval(0);
    const float gR = icval(kNX - 1);

    // Region is 2-aligned; each lane's 2 cells are all-in or all-out of domain.
    const bool  laneIn  = (gi0 >= 0) && (gi0 < kNX);
    const float gvv     = (gi0 < 0) ? gL : gR;
    const float gxv     = gvv - 0.5f;              // pinned value in x-space
    const bool  edgeBlk = (k == 0) || (k == 31);   // only these ever pin

    // ---- seed at t=0 from IC (state in x = u - 1/2 space) ----
    float x0 = (laneIn ? icval(gi0)     : gvv) - 0.5f;
    float x1 = (laneIn ? icval(gi0 + 1) : gvv) - 0.5f;

    // Lanes 16..47 own exactly the chunk (cells k*64 .. k*64+63).
    const bool writer = (lane >= 16) && (lane < 48);

    if (writer) {   // row 0 = IC (off the hot loop)
        float* p0 = out + ((size_t)b * kNT) * kNX;
        *reinterpret_cast<float2*>(p0 + gi0) = make_float2(x0 + 0.5f, x1 + 0.5f);
    }

    // Unconditional per-step store: writer lanes walk the output rows; the
    // other 32 lanes hit a per-block dump (halo slot s=0, never read) with
    // increment 0. No exec-mask branch in the hot loop.
    const int dumpIdx = (lane < 16) ? lane : (lane - 32);   // 0..31
    float* pstore = writer
        ? out + ((size_t)b * kNT + 1) * kNX + gi0
        : reinterpret_cast<float*>(halo + (size_t)p * kNS * kChunk) + 2 * dumpIdx;
    const size_t incB = writer ? (size_t)kNX * sizeof(float) : 0;

    const int fbase = p * kNS;

    // Per step: 2 parallel DPP + 3 max3 + 3 mul + 2 sub + 2 fma (+2 edge-only).
    // Chain is dpp->max3->mul->sub->fma (5 hops) — same depth as the C=4 step;
    // R18's serialized G-dpp (dpp->max3->mul->dpp->fma per step) is gone: the
    // right face is recomputed from dpp'd x instead of shifting G.
    auto do_step = [&]() {
        float xm = dpp_shr1(x1);      // x of cell gi0-1
        float xp = dpp_shl1(x0);      // x of cell gi0+2 (next lane's first)
        float m0 = max3n(xm, x0);     // face left of cell0
        float m1 = max3n(x0, x1);     // face cell0|cell1
        float m2 = max3n(x1, xp);     // face right of cell1 (recomputed)
        float G0 = m0 * m0, G1 = m1 * m1, G2 = m2 * m2;
        x0 = __builtin_fmaf(lam, G1 - G0, x0);
        x1 = __builtin_fmaf(lam, G2 - G1, x1);
        if (edgeBlk) {   // wave-uniform; skipped by 30/32 blocks
            x0 = laneIn ? x0 : gxv;
            x1 = laneIn ? x1 : gxv;
        }
    };

    auto step_store = [&]() {
        do_step();
        *reinterpret_cast<float2*>(pstore) = make_float2(x0 + 0.5f, x1 + 0.5f);
        pstore = reinterpret_cast<float*>(reinterpret_cast<char*>(pstore) + incB);
    };

#pragma unroll 1
    for (int s = 0; s < kNS; ++s) {
        // ---- re-seed halo lanes from neighbors (state at time 32*s) ----
        if (s > 0) {
            const bool needL = (k > 0), needR = (k < 31);
            if (lane == 0) {   // lane-0-only poll; whole wave waits on branch
                const int* fL = flags + (p - 1) * kNS + s;
                const int* fR = flags + (p + 1) * kNS + s;
                int okL = needL ? 0 : 1, okR = needR ? 0 : 1;
                for (int it = 0; it < (1 << 22); ++it) {
                    if (!okL) okL = mall_loadi(fL);
                    if (!okR) okR = mall_loadi(fR);
                    if (okL && okR) break;
                    __builtin_amdgcn_s_sleep(1);
                }
            }
            asm volatile("" ::: "memory");   // keep data reads below the spin

            if (lane < 16) {
                if (needL) {  // left neighbor's cells 32..63
                    const int* hp = halo + ((size_t)((p - 1) * kNS + s)) * kChunk
                                  + 32 + 2 * lane;
                    x0 = mall_loadf(hp)     - 0.5f;
                    x1 = mall_loadf(hp + 1) - 0.5f;
                }  // k==0: lanes stay pinned
            } else if (lane >= 48) {
                if (needR) {  // right neighbor's cells 0..31
                    const int* hp = halo + ((size_t)((p + 1) * kNS + s)) * kChunk
                                  + 2 * (lane - 48);
                    x0 = mall_loadf(hp)     - 0.5f;
                    x1 = mall_loadf(hp + 1) - 0.5f;
                }  // k==31: lanes stay pinned
            }
            // lanes 16..47 keep their registers (own chunk, still valid)
        }

        // ---- steps: 4 octets (last superstep: 3 octets + 7) ----
        const int noct = (s == kNS - 1) ? 3 : 4;
#pragma unroll 1
        for (int g = 0; g < noct; ++g) {
#pragma unroll
            for (int q = 0; q < 8; ++q) step_store();
        }
        if (s == kNS - 1) {
#pragma unroll
            for (int q = 0; q < 7; ++q) step_store();   // rows 505..511
        }

        // ---- publish own chunk state (time 32*(s+1)) + flag, all relaxed ----
        if (s < kNS - 1) {
            if (writer) {
                int* hp = halo + ((size_t)(fbase + (s + 1))) * kChunk + 2 * (lane - 16);
                mall_store(hp,     x0 + 0.5f);
                mall_store(hp + 1, x1 + 0.5f);
            }
            // drain data exchs (vmcnt covers global atomics), then set flag
            asm volatile("s_waitcnt vmcnt(0)" ::: "memory");
            if (lane == 0)
                (void)__hip_atomic_exchange(flags + fbase + (s + 1), 1,
                                            __ATOMIC_RELAXED, __HIP_MEMORY_SCOPE_AGENT);
        }
    }
}

}  // namespace

extern "C" void kernel_launch(void* const* d_in, const int* in_sizes, int n_in,
                              void* d_out, int out_size, void* d_ws, size_t ws_size,
                              hipStream_t stream) {
    const float* xs  = (const float*)d_in[0];
    const float* ks  = (const float*)d_in[1];
    const int*   pm  = (const int*)d_in[2];
    const float* dxv = (const float*)d_in[3];
    const float* dtv = (const float*)d_in[4];
    // d_in[5] = t_coords: only carries the (NT, NX) shape; values unused.
    float* out = (float*)d_out;

    int* flags = (int*)d_ws;
    int* halo  = (int*)((char*)d_ws + kHaloOff);

    // Flags must be zeroed every call (d_ws is not re-poisoned between replays).
    hipMemsetAsync(flags, 0, kFlagsBytes, stream);

    hipLaunchKernelGGL(godunov_fused, dim3(kSolver), dim3(64), 0, stream,
                       xs, ks, pm, dxv, dtv, out, flags, halo);
}

// Round 21
// 62.913 us; speedup vs baseline: 1.1807x; 1.1807x over previous
//
#include <hip/hip_runtime.h>

namespace {

constexpr int kB  = 16;    // batches
constexpr int kP  = 8;     // pieces
constexpr int kNT = 512;   // time steps (incl. t=0)
constexpr int kNX = 2048;  // cells
constexpr int kW  = 64;    // steps per super-step
constexpr int kChunk = 128;               // cells owned per wave
constexpr int kNS = 8;                    // super-steps: 7*64 + 63 = 511 rows
constexpr int kSolver = 256;              // 16 batches x 16 chunks

// d_ws layout
constexpr size_t kFlagsBytes = (size_t)kSolver * kNS * 4;   // 8 KB
constexpr size_t kHaloOff    = 32768;  // int halo[256][kNS][kChunk]; slot s=0 of
                                       // each block is never read -> per-block
                                       // dump target for non-writer lanes.

typedef float v2f __attribute__((ext_vector_type(2)));

// Cross-lane shift by one lane via DPP (VALU; no LDS round-trip).
__device__ __forceinline__ float dpp_shr1(float x) {
    return __builtin_bit_cast(float,
        __builtin_amdgcn_update_dpp(0, __builtin_bit_cast(int, x), 0x138, 0xF, 0xF, true));
}
__device__ __forceinline__ float dpp_shl1(float x) {
    return __builtin_bit_cast(float,
        __builtin_amdgcn_update_dpp(0, __builtin_bit_cast(int, x), 0x130, 0xF, 0xF, true));
}

// m = max(-xL, xR, 0) in ONE VOP3 (neg modifier free). Godunov flux for
// f(u)=u(1-u) in x=u-1/2 space: F = 1/4 - m^2; the 1/4 cancels in the flux
// difference, so the update is x += lam*(G_r - G_l), G = m^2.
__device__ __forceinline__ float max3n(float xL, float xR) {
    float m;
    asm("v_max3_f32 %0, -%1, %2, 0" : "=v"(m) : "v"(xL), "v"(xR));
    return m;
}

// Agent-scope coherence-point ops (relaxed: no cache maintenance).
__device__ __forceinline__ void mall_store(int* p, float v) {
    (void)__hip_atomic_exchange(p, __builtin_bit_cast(int, v),
                                __ATOMIC_RELAXED, __HIP_MEMORY_SCOPE_AGENT);
}
__device__ __forceinline__ float mall_loadf(const int* p) {
    return __builtin_bit_cast(float,
        __hip_atomic_load(p, __ATOMIC_RELAXED, __HIP_MEMORY_SCOPE_AGENT));
}
__device__ __forceinline__ int mall_loadi(const int* p) {
    return __hip_atomic_load(p, __ATOMIC_RELAXED, __HIP_MEMORY_SCOPE_AGENT);
}

__global__ __launch_bounds__(64)
void godunov_fused(const float* __restrict__ xs,   // (B, P+1)
                   const float* __restrict__ ks,   // (B, P)
                   const int*   __restrict__ pm,   // (B, P)
                   const float* __restrict__ dxp,  // (B,)
                   const float* __restrict__ dtp,  // (B,)
                   float* __restrict__ out,        // (B,1,NT,NX) fp32
                   int*   __restrict__ flags,      // [256][kNS], pre-zeroed
                   int*   __restrict__ halo)       // [256][kNS][kChunk] f32 bits
{
    const int p    = blockIdx.x;
    const int b    = p >> 4;         // batch
    const int k    = p & 15;         // chunk within batch
    const int lane = threadIdx.x;    // 0..63, one wave per block
    const int rs   = k * kChunk - kW;    // region start (may be <0)
    const int gi0  = rs + 4 * lane;      // this lane's first cell

    const float dxv = dxp[0];
    const float lam = dtp[0] / dxv;
    const v2f  lam2 = {lam, lam};
    const v2f  h2   = {0.5f, 0.5f};

    // ---- piecewise-constant IC parameters ----
    int np = 0;
    float bnds[kP];
#pragma unroll
    for (int j = 0; j < kP; ++j) {
        int m = pm[b * kP + j];
        np += m;
        bnds[j] = m ? xs[b * (kP + 1) + j + 1] : __builtin_inff();
    }
    const int cap = np - 1;

    auto icval = [&](int gi) -> float {
        float xc = ((float)gi + 0.5f) * dxv;
        int idx = 0;
#pragma unroll
        for (int j = 0; j < kP; ++j) idx += (xc >= bnds[j]) ? 1 : 0;
        idx = min(idx, cap);
        return ks[b * kP + idx];
    };

    // Constant ghost values (reference: frozen IC endpoints).
    const float gL = icval(0);
    const float gR = icval(kNX - 1);

    // Region is 4-aligned; each lane's 4 cells are all-in or all-out of domain.
    const bool  laneIn  = (gi0 >= 0) && (gi0 < kNX);
    const float gvv     = (gi0 < 0) ? gL : gR;
    const float gxv     = gvv - 0.5f;              // pinned value in x-space
    const bool  edgeBlk = (k == 0) || (k == 15);   // only these ever pin

    // ---- seed at t=0 from IC (state in x = u - 1/2 space, packed pairs) ----
    v2f x01, x23;
    x01.x = (laneIn ? icval(gi0)     : gvv) - 0.5f;
    x01.y = (laneIn ? icval(gi0 + 1) : gvv) - 0.5f;
    x23.x = (laneIn ? icval(gi0 + 2) : gvv) - 0.5f;
    x23.y = (laneIn ? icval(gi0 + 3) : gvv) - 0.5f;

    // Lanes 16..47 own exactly the chunk (cells k*128 .. k*128+127).
    const bool writer = (lane >= 16) && (lane < 48);

    if (writer) {   // row 0 = IC (off the hot loop)
        float* p0 = out + ((size_t)b * kNT) * kNX;
        *reinterpret_cast<float4*>(p0 + gi0) =
            make_float4(x01.x + 0.5f, x01.y + 0.5f, x23.x + 0.5f, x23.y + 0.5f);
    }

    // Unconditional stores: writer lanes walk output rows; other 32 lanes hit
    // a per-block dump (halo slot s=0, never read) with increment 0.
    const int dumpIdx = (lane < 16) ? lane : (lane - 32);   // 0..31
    char* pstore = writer
        ? (char*)(out + ((size_t)b * kNT + 1) * kNX + gi0)
        : (char*)(reinterpret_cast<float*>(halo + (size_t)p * kNS * kChunk) + 4 * dumpIdx);
    const size_t incB = writer ? (size_t)kNX * sizeof(float) : 0;

    const int fbase = p * kNS;

    // Packed step: 2 dpp + 5 max3 + 2 pk_mul + 1 mul + 4 sub + 2 pk_fma
    // (+2 pk_add in the store path). Element extracts are free subreg reads.
    auto do_step = [&]() {
        float xm = dpp_shr1(x23.y);   // x of cell gi0-1
        float xp = dpp_shl1(x01.x);   // x of cell gi0+4
        float m0 = max3n(xm,    x01.x);
        float m1 = max3n(x01.x, x01.y);
        float m2 = max3n(x01.y, x23.x);
        float m3 = max3n(x23.x, x23.y);
        float m4 = max3n(x23.y, xp);
        v2f mA = {m0, m1}, mB = {m2, m3};
        v2f GA = mA * mA;             // v_pk_mul_f32
        v2f GB = mB * mB;             // v_pk_mul_f32
        float G4 = m4 * m4;
        v2f d01 = {GA.y - GA.x, GB.x - GA.y};
        v2f d23 = {GB.y - GB.x, G4   - GB.y};
        x01 = lam2 * d01 + x01;       // v_pk_fma_f32
        x23 = lam2 * d23 + x23;       // v_pk_fma_f32
        if (edgeBlk) {   // wave-uniform; skipped by 14/16 blocks
            x01.x = laneIn ? x01.x : gxv;
            x01.y = laneIn ? x01.y : gxv;
            x23.x = laneIn ? x23.x : gxv;
            x23.y = laneIn ? x23.y : gxv;
        }
    };

    auto step_store = [&]() {
        do_step();
        v2f s01 = x01 + h2;           // v_pk_add_f32
        v2f s23 = x23 + h2;           // v_pk_add_f32
        *reinterpret_cast<float4*>(pstore) = make_float4(s01.x, s01.y, s23.x, s23.y);
        pstore += incB;
    };

#pragma unroll 1
    for (int s = 0; s < kNS; ++s) {
        // ---- re-seed halo lanes from neighbors (state at time 64*s) ----
        if (s > 0) {
            const bool needL = (k > 0), needR = (k < 15);
            if (lane == 0) {   // lane-0-only poll; whole wave waits on branch
                const int* fL = flags + (p - 1) * kNS + s;
                const int* fR = flags + (p + 1) * kNS + s;
                int okL = needL ? 0 : 1, okR = needR ? 0 : 1;
                for (int it = 0; it < (1 << 22); ++it) {
                    if (!okL) okL = mall_loadi(fL);
                    if (!okR) okR = mall_loadi(fR);
                    if (okL && okR) break;
                    __builtin_amdgcn_s_sleep(1);
                }
            }
            asm volatile("" ::: "memory");   // keep data reads below the spin

            if (lane < 16) {
                if (needL) {  // left neighbor's cells 64..127
                    const int* hp = halo + ((size_t)((p - 1) * kNS + s)) * kChunk
                                  + 64 + 4 * lane;
                    x01.x = mall_loadf(hp)     - 0.5f;
                    x01.y = mall_loadf(hp + 1) - 0.5f;
                    x23.x = mall_loadf(hp + 2) - 0.5f;
                    x23.y = mall_loadf(hp + 3) - 0.5f;
                }  // k==0: lanes stay pinned
            } else if (lane >= 48) {
                if (needR) {  // right neighbor's cells 0..63
                    const int* hp = halo + ((size_t)((p + 1) * kNS + s)) * kChunk
                                  + 4 * (lane - 48);
                    x01.x = mall_loadf(hp)     - 0.5f;
                    x01.y = mall_loadf(hp + 1) - 0.5f;
                    x23.x = mall_loadf(hp + 2) - 0.5f;
                    x23.y = mall_loadf(hp + 3) - 0.5f;
                }  // k==15: lanes stay pinned
            }
            // lanes 16..47 keep their registers (own chunk, still valid)
        }

        // ---- steps: 8 octets (last superstep: 7 octets + 7) ----
        const int noct = (s == kNS - 1) ? 7 : 8;
#pragma unroll 1
        for (int g = 0; g < noct; ++g) {
#pragma unroll
            for (int q = 0; q < 8; ++q) step_store();
        }
        if (s == kNS - 1) {
#pragma unroll
            for (int q = 0; q < 7; ++q) step_store();   // rows 505..511
        }

        // ---- publish own chunk state (time 64*(s+1)) + flag, all relaxed ----
        if (s < kNS - 1) {
            if (writer) {
                int* hp = halo + ((size_t)(fbase + (s + 1))) * kChunk + 4 * (lane - 16);
                mall_store(hp,     x01.x + 0.5f);
                mall_store(hp + 1, x01.y + 0.5f);
                mall_store(hp + 2, x23.x + 0.5f);
                mall_store(hp + 3, x23.y + 0.5f);
            }
            // drain data exchs (vmcnt covers global atomics), then set flag
            asm volatile("s_waitcnt vmcnt(0)" ::: "memory");
            if (lane == 0)
                (void)__hip_atomic_exchange(flags + fbase + (s + 1), 1,
                                            __ATOMIC_RELAXED, __HIP_MEMORY_SCOPE_AGENT);
        }
    }
}

}  // namespace

extern "C" void kernel_launch(void* const* d_in, const int* in_sizes, int n_in,
                              void* d_out, int out_size, void* d_ws, size_t ws_size,
                              hipStream_t stream) {
    const float* xs  = (const float*)d_in[0];
    const float* ks  = (const float*)d_in[1];
    const int*   pm  = (const int*)d_in[2];
    const float* dxv = (const float*)d_in[3];
    const float* dtv = (const float*)d_in[4];
    // d_in[5] = t_coords: only carries the (NT, NX) shape; values unused.
    float* out = (float*)d_out;

    int* flags = (int*)d_ws;
    int* halo  = (int*)((char*)d_ws + kHaloOff);

    // Flags must be zeroed every call (d_ws is not re-poisoned between replays).
    hipMemsetAsync(flags, 0, kFlagsBytes, stream);

    hipLaunchKernelGGL(godunov_fused, dim3(kSolver), dim3(64), 0, stream,
                       xs, ks, pm, dxv, dtv, out, flags, halo);
}

// Round 22
// 57.301 us; speedup vs baseline: 1.2964x; 1.0979x over previous
//
#include <hip/hip_runtime.h>

namespace {

constexpr int kB  = 16;    // batches
constexpr int kP  = 8;     // pieces
constexpr int kNT = 512;   // time steps (incl. t=0)
constexpr int kNX = 2048;  // cells
constexpr int kW  = 64;    // steps per super-step
constexpr int kChunk = 128;               // cells owned per wave
constexpr int kNS = 8;                    // super-steps: 7*64 + 63 = 511 rows
constexpr int kSolver = 256;              // 16 batches x 16 chunks

// d_ws layout: halo only (data-as-flag sync; no flag array).
// halo[256][kNS][kChunk] f32; slot s=0 of each block is never read -> dump
// target for non-writer lanes. Whole buffer poisoned to 0xFFFFFFFF (-NaN,
// unreachable by any real u in [0,1]) each call; consumers poll their own
// words until != poison. One writer per word per slot -> any non-poison
// read is the true value; no flags, no drains, no acquire/release.
constexpr size_t kHaloBytes = (size_t)kSolver * kNS * kChunk * 4;   // 1 MB
constexpr int    kPoison    = -1;                                    // 0xFFFFFFFF

typedef float v2f __attribute__((ext_vector_type(2)));

// Cross-lane shift by one lane via DPP (VALU; no LDS round-trip).
__device__ __forceinline__ float dpp_shr1(float x) {
    return __builtin_bit_cast(float,
        __builtin_amdgcn_update_dpp(0, __builtin_bit_cast(int, x), 0x138, 0xF, 0xF, true));
}
__device__ __forceinline__ float dpp_shl1(float x) {
    return __builtin_bit_cast(float,
        __builtin_amdgcn_update_dpp(0, __builtin_bit_cast(int, x), 0x130, 0xF, 0xF, true));
}

// m = max(-xL, xR, 0) in ONE VOP3 (neg modifier free). Godunov flux for
// f(u)=u(1-u) in x=u-1/2 space: F = 1/4 - m^2; the 1/4 cancels in the flux
// difference, so the update is x += lam*(G_r - G_l), G = m^2.
__device__ __forceinline__ float max3n(float xL, float xR) {
    float m;
    asm("v_max3_f32 %0, -%1, %2, 0" : "=v"(m) : "v"(xL), "v"(xR));
    return m;
}

// Agent-scope coherence-point ops (relaxed: no cache maintenance).
__device__ __forceinline__ void mall_store(int* p, float v) {
    (void)__hip_atomic_exchange(p, __builtin_bit_cast(int, v),
                                __ATOMIC_RELAXED, __HIP_MEMORY_SCOPE_AGENT);
}
__device__ __forceinline__ int mall_loadi(const int* p) {
    return __hip_atomic_load(p, __ATOMIC_RELAXED, __HIP_MEMORY_SCOPE_AGENT);
}

__global__ __launch_bounds__(64)
void godunov_fused(const float* __restrict__ xs,   // (B, P+1)
                   const float* __restrict__ ks,   // (B, P)
                   const int*   __restrict__ pm,   // (B, P)
                   const float* __restrict__ dxp,  // (B,)
                   const float* __restrict__ dtp,  // (B,)
                   float* __restrict__ out,        // (B,1,NT,NX) fp32
                   int*   __restrict__ halo)       // [256][kNS][kChunk], poisoned
{
    const int p    = blockIdx.x;
    const int b    = p >> 4;         // batch
    const int k    = p & 15;         // chunk within batch
    const int lane = threadIdx.x;    // 0..63, one wave per block
    const int rs   = k * kChunk - kW;    // region start (may be <0)
    const int gi0  = rs + 4 * lane;      // this lane's first cell

    const float dxv = dxp[0];
    const float lam = dtp[0] / dxv;
    const v2f  lam2 = {lam, lam};
    const v2f  h2   = {0.5f, 0.5f};

    // ---- piecewise-constant IC parameters ----
    int np = 0;
    float bnds[kP];
#pragma unroll
    for (int j = 0; j < kP; ++j) {
        int m = pm[b * kP + j];
        np += m;
        bnds[j] = m ? xs[b * (kP + 1) + j + 1] : __builtin_inff();
    }
    const int cap = np - 1;

    auto icval = [&](int gi) -> float {
        float xc = ((float)gi + 0.5f) * dxv;
        int idx = 0;
#pragma unroll
        for (int j = 0; j < kP; ++j) idx += (xc >= bnds[j]) ? 1 : 0;
        idx = min(idx, cap);
        return ks[b * kP + idx];
    };

    // Constant ghost values (reference: frozen IC endpoints).
    const float gL = icval(0);
    const float gR = icval(kNX - 1);

    // Region is 4-aligned; each lane's 4 cells are all-in or all-out of domain.
    const bool  laneIn  = (gi0 >= 0) && (gi0 < kNX);
    const float gvv     = (gi0 < 0) ? gL : gR;
    const float gxv     = gvv - 0.5f;              // pinned value in x-space
    const bool  edgeBlk = (k == 0) || (k == 15);   // only these ever pin

    // ---- seed at t=0 from IC (state in x = u - 1/2 space, packed pairs) ----
    v2f x01, x23;
    x01.x = (laneIn ? icval(gi0)     : gvv) - 0.5f;
    x01.y = (laneIn ? icval(gi0 + 1) : gvv) - 0.5f;
    x23.x = (laneIn ? icval(gi0 + 2) : gvv) - 0.5f;
    x23.y = (laneIn ? icval(gi0 + 3) : gvv) - 0.5f;

    // Lanes 16..47 own exactly the chunk (cells k*128 .. k*128+127).
    const bool writer = (lane >= 16) && (lane < 48);

    if (writer) {   // row 0 = IC (off the hot loop)
        float* p0 = out + ((size_t)b * kNT) * kNX;
        *reinterpret_cast<float4*>(p0 + gi0) =
            make_float4(x01.x + 0.5f, x01.y + 0.5f, x23.x + 0.5f, x23.y + 0.5f);
    }

    // Unconditional stores: writer lanes walk output rows; other 32 lanes hit
    // a per-block dump (halo slot s=0, never read) with increment 0.
    const int dumpIdx = (lane < 16) ? lane : (lane - 32);   // 0..31
    char* pstore = writer
        ? (char*)(out + ((size_t)b * kNT + 1) * kNX + gi0)
        : (char*)(reinterpret_cast<float*>(halo + (size_t)p * kNS * kChunk) + 4 * dumpIdx);
    const size_t incB = writer ? (size_t)kNX * sizeof(float) : 0;

    // Packed step: 2 dpp + 5 max3 + 2 pk_mul + 1 mul + 4 sub + 2 pk_fma
    // (+2 pk_add in the store path). Element extracts are free subreg reads.
    auto do_step = [&]() {
        float xm = dpp_shr1(x23.y);   // x of cell gi0-1
        float xp = dpp_shl1(x01.x);   // x of cell gi0+4
        float m0 = max3n(xm,    x01.x);
        float m1 = max3n(x01.x, x01.y);
        float m2 = max3n(x01.y, x23.x);
        float m3 = max3n(x23.x, x23.y);
        float m4 = max3n(x23.y, xp);
        v2f mA = {m0, m1}, mB = {m2, m3};
        v2f GA = mA * mA;             // v_pk_mul_f32
        v2f GB = mB * mB;             // v_pk_mul_f32
        float G4 = m4 * m4;
        v2f d01 = {GA.y - GA.x, GB.x - GA.y};
        v2f d23 = {GB.y - GB.x, G4   - GB.y};
        x01 = lam2 * d01 + x01;       // v_pk_fma_f32
        x23 = lam2 * d23 + x23;       // v_pk_fma_f32
        if (edgeBlk) {   // wave-uniform; skipped by 14/16 blocks
            x01.x = laneIn ? x01.x : gxv;
            x01.y = laneIn ? x01.y : gxv;
            x23.x = laneIn ? x23.x : gxv;
            x23.y = laneIn ? x23.y : gxv;
        }
    };

    auto step_store = [&]() {
        do_step();
        v2f s01 = x01 + h2;           // v_pk_add_f32
        v2f s23 = x23 + h2;           // v_pk_add_f32
        *reinterpret_cast<float4*>(pstore) = make_float4(s01.x, s01.y, s23.x, s23.y);
        pstore += incB;
    };

#pragma unroll 1
    for (int s = 0; s < kNS; ++s) {
        // ---- re-seed halo lanes from neighbors (state at time 64*s) ----
        // Data-as-flag: each halo lane polls ITS OWN 4 words until none is
        // the poison pattern; values are then used directly. No flags.
        if (s > 0) {
            const bool needL = (k > 0), needR = (k < 15);
            if (lane < 16) {
                if (needL) {  // left neighbor's cells 64..127
                    const int* hp = halo + ((size_t)((p - 1) * kNS + s)) * kChunk
                                  + 64 + 4 * lane;
                    int v0, v1, v2, v3;
                    for (int it = 0; it < (1 << 22); ++it) {
                        v0 = mall_loadi(hp);     v1 = mall_loadi(hp + 1);
                        v2 = mall_loadi(hp + 2); v3 = mall_loadi(hp + 3);
                        if (v0 != kPoison && v1 != kPoison &&
                            v2 != kPoison && v3 != kPoison) break;
                        __builtin_amdgcn_s_sleep(1);
                    }
                    x01.x = __builtin_bit_cast(float, v0) - 0.5f;
                    x01.y = __builtin_bit_cast(float, v1) - 0.5f;
                    x23.x = __builtin_bit_cast(float, v2) - 0.5f;
                    x23.y = __builtin_bit_cast(float, v3) - 0.5f;
                }  // k==0: lanes stay pinned
            } else if (lane >= 48) {
                if (needR) {  // right neighbor's cells 0..63
                    const int* hp = halo + ((size_t)((p + 1) * kNS + s)) * kChunk
                                  + 4 * (lane - 48);
                    int v0, v1, v2, v3;
                    for (int it = 0; it < (1 << 22); ++it) {
                        v0 = mall_loadi(hp);     v1 = mall_loadi(hp + 1);
                        v2 = mall_loadi(hp + 2); v3 = mall_loadi(hp + 3);
                        if (v0 != kPoison && v1 != kPoison &&
                            v2 != kPoison && v3 != kPoison) break;
                        __builtin_amdgcn_s_sleep(1);
                    }
                    x01.x = __builtin_bit_cast(float, v0) - 0.5f;
                    x01.y = __builtin_bit_cast(float, v1) - 0.5f;
                    x23.x = __builtin_bit_cast(float, v2) - 0.5f;
                    x23.y = __builtin_bit_cast(float, v3) - 0.5f;
                }  // k==15: lanes stay pinned
            }
            // lanes 16..47 keep their registers (own chunk, still valid)
        }

        // ---- steps: 8 octets (last superstep: 7 octets + 7) ----
        const int noct = (s == kNS - 1) ? 7 : 8;
#pragma unroll 1
        for (int g = 0; g < noct; ++g) {
#pragma unroll
            for (int q = 0; q < 8; ++q) step_store();
        }
        if (s == kNS - 1) {
#pragma unroll
            for (int q = 0; q < 7; ++q) step_store();   // rows 505..511
        }

        // ---- publish own chunk state (time 64*(s+1)): fire-and-forget ----
        if (s < kNS - 1 && writer) {
            int* hp = halo + ((size_t)(p * kNS + (s + 1))) * kChunk + 4 * (lane - 16);
            mall_store(hp,     x01.x + 0.5f);
            mall_store(hp + 1, x01.y + 0.5f);
            mall_store(hp + 2, x23.x + 0.5f);
            mall_store(hp + 3, x23.y + 0.5f);
        }
    }
}

}  // namespace

extern "C" void kernel_launch(void* const* d_in, const int* in_sizes, int n_in,
                              void* d_out, int out_size, void* d_ws, size_t ws_size,
                              hipStream_t stream) {
    const float* xs  = (const float*)d_in[0];
    const float* ks  = (const float*)d_in[1];
    const int*   pm  = (const int*)d_in[2];
    const float* dxv = (const float*)d_in[3];
    const float* dtv = (const float*)d_in[4];
    // d_in[5] = t_coords: only carries the (NT, NX) shape; values unused.
    float* out = (float*)d_out;

    int* halo = (int*)d_ws;

    // Re-poison the halo every call (d_ws is not re-poisoned between replays).
    // 0xFF bytes -> every word reads 0xFFFFFFFF (-NaN), unreachable by data.
    hipMemsetAsync(halo, 0xFF, kHaloBytes, stream);

    hipLaunchKernelGGL(godunov_fused, dim3(kSolver), dim3(64), 0, stream,
                       xs, ks, pm, dxv, dtv, out, halo);
}

// Round 23
// 47.077 us; speedup vs baseline: 1.5779x; 1.2172x over previous
//
#include <hip/hip_runtime.h>

namespace {

constexpr int kB  = 16;    // batches
constexpr int kP  = 8;     // pieces
constexpr int kNT = 512;   // time steps (incl. t=0)
constexpr int kNX = 2048;  // cells
constexpr int kW  = 48;    // steps per super-step
constexpr int kOwn = 32;   // cells owned per wave
constexpr int kNS = 11;    // super-steps: 10*48 + 31 = 511 rows
constexpr int kCpB = 64;   // chunks per batch
constexpr int kSolver = kB * kCpB;        // 1024 blocks, 1 wave each
// region per wave = kOwn + 2*kW = 128 cells = 64 lanes x 2 cells

// d_ws: halo[kNS][kB][kNX] f32-bits, data-as-flag (poisoned 0xFFFFFFFF each
// call; any real value is u in [0,1] -> distinguishable). Slot s is written
// by every block's owned 32 cells at time 48s (global-cell indexed, so the
// 48-wide halo spanning two producer blocks needs no block arithmetic).
// Slot 0 is never read -> dump target for non-writer lanes' stores.
constexpr size_t kHaloBytes = (size_t)kNS * kB * kNX * 4;   // ~1.4 MB
constexpr int    kPoison    = -1;                           // 0xFFFFFFFF

typedef float v2f __attribute__((ext_vector_type(2)));

// Cross-lane shift by one lane via DPP (VALU; no LDS round-trip).
__device__ __forceinline__ float dpp_shr1(float x) {
    return __builtin_bit_cast(float,
        __builtin_amdgcn_update_dpp(0, __builtin_bit_cast(int, x), 0x138, 0xF, 0xF, true));
}
__device__ __forceinline__ float dpp_shl1(float x) {
    return __builtin_bit_cast(float,
        __builtin_amdgcn_update_dpp(0, __builtin_bit_cast(int, x), 0x130, 0xF, 0xF, true));
}

// m = max(-xL, xR, 0) in ONE VOP3. Godunov flux for f(u)=u(1-u) in x=u-1/2
// space: F = 1/4 - m^2; the 1/4 cancels in the flux difference.
__device__ __forceinline__ float max3n(float xL, float xR) {
    float m;
    asm("v_max3_f32 %0, -%1, %2, 0" : "=v"(m) : "v"(xL), "v"(xR));
    return m;
}

// Agent-scope coherence-point ops (relaxed: no cache maintenance).
__device__ __forceinline__ void mall_store(int* p, float v) {
    (void)__hip_atomic_exchange(p, __builtin_bit_cast(int, v),
                                __ATOMIC_RELAXED, __HIP_MEMORY_SCOPE_AGENT);
}
__device__ __forceinline__ int mall_loadi(const int* p) {
    return __hip_atomic_load(p, __ATOMIC_RELAXED, __HIP_MEMORY_SCOPE_AGENT);
}

__global__ __launch_bounds__(64)
void godunov_fused(const float* __restrict__ xs,   // (B, P+1)
                   const float* __restrict__ ks,   // (B, P)
                   const int*   __restrict__ pm,   // (B, P)
                   const float* __restrict__ dxp,  // (B,)
                   const float* __restrict__ dtp,  // (B,)
                   float* __restrict__ out,        // (B,1,NT,NX) fp32
                   int*   __restrict__ halo)       // [kNS][kB][kNX], poisoned
{
    const int p    = blockIdx.x;
    const int b    = p >> 6;         // batch
    const int k    = p & 63;         // chunk within batch
    const int lane = threadIdx.x;    // 0..63, one wave per block
    const int rs   = k * kOwn - kW;  // region start (may be <0)
    const int gi0  = rs + 2 * lane;  // this lane's first cell

    const float dxv = dxp[0];
    const float lam = dtp[0] / dxv;
    const v2f  h2   = {0.5f, 0.5f};

    // ---- piecewise-constant IC parameters ----
    int np = 0;
    float bnds[kP];
#pragma unroll
    for (int j = 0; j < kP; ++j) {
        int m = pm[b * kP + j];
        np += m;
        bnds[j] = m ? xs[b * (kP + 1) + j + 1] : __builtin_inff();
    }
    const int cap = np - 1;

    auto icval = [&](int gi) -> float {
        float xc = ((float)gi + 0.5f) * dxv;
        int idx = 0;
#pragma unroll
        for (int j = 0; j < kP; ++j) idx += (xc >= bnds[j]) ? 1 : 0;
        idx = min(idx, cap);
        return ks[b * kP + idx];
    };

    // Constant ghost values (reference: frozen IC endpoints).
    const float gL = icval(0);
    const float gR = icval(kNX - 1);

    // Region is 2-aligned; each lane's 2 cells are all-in or all-out of domain.
    const bool  laneIn  = (gi0 >= 0) && (gi0 < kNX);
    const float gvv     = (gi0 < 0) ? gL : gR;
    const float gxv     = gvv - 0.5f;              // pinned value in x-space
    const bool  edgeBlk = (k < 2) || (k >= kCpB - 2);   // regions touching domain edge

    // ---- seed at t=0 from IC (state in x = u - 1/2 space) ----
    float x0 = (laneIn ? icval(gi0)     : gvv) - 0.5f;
    float x1 = (laneIn ? icval(gi0 + 1) : gvv) - 0.5f;

    // Lanes 24..39 own exactly the chunk (cells k*32 .. k*32+31).
    const bool writer = (lane >= 24) && (lane < 40);

    if (writer) {   // row 0 = IC (off the hot loop)
        float* p0 = out + ((size_t)b * kNT) * kNX;
        *reinterpret_cast<float2*>(p0 + gi0) = make_float2(x0 + 0.5f, x1 + 0.5f);
    }

    // Unconditional stores: writer lanes walk output rows; the other 48 lanes
    // hit a per-block dump inside never-read slot 0 (collisions harmless).
    char* pstore = writer
        ? (char*)(out + ((size_t)b * kNT + 1) * kNX + gi0)
        : (char*)(halo + p * kOwn + 2 * (lane & 15));
    const size_t incB = writer ? (size_t)kNX * sizeof(float) : 0;

    // Per step: 2 dpp + 3 max3 + 1 pk_mul + 1 mul + 4 fma + 1 pk_add + store.
    // Reassociated update keeps the DPP-dependent flux LAST: chain is
    // dpp -> max3 -> mul -> fma (4 hops).
    auto step_store = [&]() {
        float xm = dpp_shr1(x1);      // x of cell gi0-1
        float xp = dpp_shl1(x0);      // x of cell gi0+2
        float m0 = max3n(xm, x0);
        float m1 = max3n(x0, x1);
        float m2 = max3n(x1, xp);
        v2f mA = {m0, m1};
        v2f GA = mA * mA;             // v_pk_mul_f32: {G0, G1}
        float G2 = m2 * m2;
        // x0' = x0 + lam*(G1-G0); x1' = x1 + lam*(G2-G1); dpp-dep flux last
        float t0 = __builtin_fmaf( lam, GA.y, x0);
        x0       = __builtin_fmaf(-lam, GA.x, t0);
        float t1 = __builtin_fmaf(-lam, GA.y, x1);
        x1       = __builtin_fmaf( lam, G2,   t1);
        if (edgeBlk) {   // wave-uniform; skipped by 60/64 blocks
            x0 = laneIn ? x0 : gxv;
            x1 = laneIn ? x1 : gxv;
        }
        v2f xv = {x0, x1};
        v2f sv = xv + h2;             // v_pk_add_f32
        *reinterpret_cast<float2*>(pstore) = make_float2(sv.x, sv.y);
        pstore += incB;
    };

#pragma unroll 1
    for (int s = 0; s < kNS; ++s) {
        // ---- re-seed halo lanes (state at time 48*s), data-as-flag ----
        if (s > 0) {
            const int* slot = halo + ((size_t)s * kB + b) * kNX;
            if (lane < 24) {          // left halo: cells [rs, rs+48)
                if (gi0 >= 0) {       // else: stays pinned at gL
                    const int* hp = slot + gi0;
                    int v0, v1;
                    for (int it = 0; it < (1 << 22); ++it) {
                        v0 = mall_loadi(hp); v1 = mall_loadi(hp + 1);
                        if (v0 != kPoison && v1 != kPoison) break;
                        __builtin_amdgcn_s_sleep(1);
                    }
                    x0 = __builtin_bit_cast(float, v0) - 0.5f;
                    x1 = __builtin_bit_cast(float, v1) - 0.5f;
                }
            } else if (lane >= 40) {  // right halo: cells [rs+80, rs+128)
                if (gi0 < kNX) {      // else: stays pinned at gR
                    const int* hp = slot + gi0;
                    int v0, v1;
                    for (int it = 0; it < (1 << 22); ++it) {
                        v0 = mall_loadi(hp); v1 = mall_loadi(hp + 1);
                        if (v0 != kPoison && v1 != kPoison) break;
                        __builtin_amdgcn_s_sleep(1);
                    }
                    x0 = __builtin_bit_cast(float, v0) - 0.5f;
                    x1 = __builtin_bit_cast(float, v1) - 0.5f;
                }
            }
            // lanes 24..39 keep their registers (own chunk, still valid)
        }

        // ---- steps: 6 octets (last superstep: 3 octets + 7) ----
        const int noct = (s == kNS - 1) ? 3 : 6;
#pragma unroll 1
        for (int g = 0; g < noct; ++g) {
#pragma unroll
            for (int q = 0; q < 8; ++q) step_store();
        }
        if (s == kNS - 1) {
#pragma unroll
            for (int q = 0; q < 7; ++q) step_store();   // rows 505..511
        }

        // ---- publish own cells (time 48*(s+1)): fire-and-forget ----
        if (s < kNS - 1 && writer) {
            int* hp = halo + ((size_t)(s + 1) * kB + b) * kNX + gi0;
            mall_store(hp,     x0 + 0.5f);
            mall_store(hp + 1, x1 + 0.5f);
        }
    }
}

}  // namespace

extern "C" void kernel_launch(void* const* d_in, const int* in_sizes, int n_in,
                              void* d_out, int out_size, void* d_ws, size_t ws_size,
                              hipStream_t stream) {
    const float* xs  = (const float*)d_in[0];
    const float* ks  = (const float*)d_in[1];
    const int*   pm  = (const int*)d_in[2];
    const float* dxv = (const float*)d_in[3];
    const float* dtv = (const float*)d_in[4];
    // d_in[5] = t_coords: only carries the (NT, NX) shape; values unused.
    float* out = (float*)d_out;

    int* halo = (int*)d_ws;

    // Re-poison the halo every call (d_ws is not re-poisoned between replays).
    hipMemsetAsync(halo, 0xFF, kHaloBytes, stream);

    hipLaunchKernelGGL(godunov_fused, dim3(kSolver), dim3(64), 0, stream,
                       xs, ks, pm, dxv, dtv, out, halo);
}